// Round 2
// baseline (372.339 us; speedup 1.0000x reference)
//
#include <hip/hip_runtime.h>
#include <stdint.h>

// BitConv1d: out = conv1d(x, sign(w), pad=1) * mean|w| * scale
// (x_scale cancels exactly: conv(x/s,w)*s == conv(x,w))
//
// Workspace layout:
//   float[1024] @ 0      : per-block partial sums of |w|
//   float       @ 4096   : final factor = mean|w| * scale
//   ushort[786432] @ 8192: sign(w) as bf16, layout [t][ci>>3][co][ci&7]

#define CIN   512
#define COUT  512
#define LLEN  4096
#define NBAT  16
#define KW    3
#define WELEMS (COUT*CIN*KW)

typedef __bf16 bf16x8 __attribute__((ext_vector_type(8)));
typedef float  f32x4  __attribute__((ext_vector_type(4)));

__device__ __forceinline__ uint32_t f2bf(float f) {
    union { float f; uint32_t u; } v; v.f = f;
    return (v.u + 0x7fffu + ((v.u >> 16) & 1u)) >> 16;   // RNE
}

// ---- pack sign(w) -> bf16 (MFMA layout) + per-block |w| partial sums ----
__global__ __launch_bounds__(256) void pack_w(const float* __restrict__ w,
                                              unsigned short* __restrict__ wsw,
                                              float* __restrict__ partial) {
    __shared__ float red[256];
    int tid = threadIdx.x;
    int idx = blockIdx.x * 256 + tid;          // co*512 + ci
    float s = 0.f;
    int co = idx >> 9, ci = idx & 511;
#pragma unroll
    for (int t = 0; t < KW; ++t) {
        float v = w[idx * 3 + t];
        s += fabsf(v);
        unsigned short b = (v > 0.f) ? 0x3F80 : ((v < 0.f) ? 0xBF80 : 0);
        wsw[((t * 64 + (ci >> 3)) * 512 + co) * 8 + (ci & 7)] = b;
    }
    red[tid] = s;
    __syncthreads();
    for (int off = 128; off > 0; off >>= 1) {
        if (tid < off) red[tid] += red[tid + off];
        __syncthreads();
    }
    if (tid == 0) partial[blockIdx.x] = red[0];
}

__global__ __launch_bounds__(256) void wscale_final(const float* __restrict__ partial,
                                                    const float* __restrict__ scale,
                                                    float* __restrict__ fac) {
    __shared__ float red[256];
    int tid = threadIdx.x;
    red[tid] = partial[tid] + partial[tid + 256] + partial[tid + 512] + partial[tid + 768];
    __syncthreads();
    for (int off = 128; off > 0; off >>= 1) {
        if (tid < off) red[tid] += red[tid + off];
        __syncthreads();
    }
    if (tid == 0) fac[0] = red[0] * (1.0f / (float)WELEMS) * scale[0];
}

// ---------------- conv as MFMA GEMM, software-pipelined ----------------
// Block tile: 128 (co) x 128 (l), 4 waves 2x2, acc 4x4 16x16 subtiles/wave.
// Per ci-chunk (32): prefetch next chunk's A+B global->regs BEFORE compute,
// write regs->LDS after the post-compute barrier. Raw s_barrier + manual
// lgkmcnt(0) keeps the global loads in flight across barriers (no vmcnt drain).
__global__ __launch_bounds__(256, 3) void conv_mfma(const float* __restrict__ x,
                                                    const unsigned short* __restrict__ wsw,
                                                    const float* __restrict__ fac,
                                                    float* __restrict__ out) {
    // XCD-aware swizzle: 2048 blocks, 8 XCDs -> each XCD gets 256 contiguous
    // original ids; the 4 cob-blocks sharing an x tile run adjacent on one XCD.
    int swz = (blockIdx.x & 7) * 256 + (blockIdx.x >> 3);
    int cob = swz & 3;            // co tile (fastest: share x tile in L2)
    int lb  = (swz >> 2) & 31;    // l tile
    int n   = swz >> 7;           // sample
    int co0 = cob * 128;
    int l0  = lb * 128;

    __shared__ uint4 smemA[1536];   // 24576 B: [t3][ks4][co128][j8] bf16
    __shared__ uint4 smemB[520];    //  8320 B: [ll130][32ci] bf16, 64B rows, XOR swizzle
    char* As = (char*)smemA;
    char* Bs = (char*)smemB;

    int tid  = threadIdx.x;
    int wave = tid >> 6;
    int lane = tid & 63;
    int wco  = (wave >> 1) * 64;
    int wl   = (wave & 1) * 64;
    int m    = lane & 15;
    int ks   = lane >> 4;
    const int p  = tid & 15;      // ci pair (2p, 2p+1)
    const int fb = tid >> 4;      // float4 column

    const float* xbase = x + (size_t)(n * 512) * LLEN;

    // prefetch registers
    uint4  aReg[6];
    float4 b0[2], b1[2];
    float  hReg = 0.f;

    auto LOADA = [&](int c) {
#pragma unroll
        for (int it = 0; it < 6; ++it) {
            int g = it * 256 + tid;              // 0..1535 uint4
            int s = g >> 7;                      // = t*4+ks
            int r = g & 127;                     // co within tile
            aReg[it] = *reinterpret_cast<const uint4*>(
                wsw + ((((s >> 2) * 64 + c * 4 + (s & 3)) * 512) + (co0 + r)) * 8);
        }
    };
    auto LOADB = [&](int c) {
        const float* xrow0 = xbase + (size_t)(c * 32 + 2 * p) * LLEN + l0;
        const float* xrow1 = xrow0 + LLEN;
        b0[0] = reinterpret_cast<const float4*>(xrow0)[fb];
        b1[0] = reinterpret_cast<const float4*>(xrow1)[fb];
        b0[1] = reinterpret_cast<const float4*>(xrow0)[fb + 16];
        b1[1] = reinterpret_cast<const float4*>(xrow1)[fb + 16];
        if (tid < 32)
            hReg = (l0 > 0) ? xbase[(size_t)(c * 32 + tid) * LLEN + l0 - 1] : 0.f;
        else if (tid < 64)
            hReg = (l0 + 128 < LLEN) ? xbase[(size_t)(c * 32 + tid - 32) * LLEN + l0 + 128] : 0.f;
    };
    auto WRITE = [&]() {
#pragma unroll
        for (int it = 0; it < 6; ++it) smemA[it * 256 + tid] = aReg[it];
        int kslot = p >> 2, jj = (2 * p) & 7;
#pragma unroll
        for (int half = 0; half < 2; ++half) {
            int f = fb + half * 16;
#pragma unroll
            for (int e = 0; e < 4; ++e) {
                int ll = f * 4 + 1 + e;                       // 1..128
                uint32_t pk = f2bf(((const float*)&b0[half])[e])
                            | (f2bf(((const float*)&b1[half])[e]) << 16);
                int off = ll * 64 + ((kslot ^ ((ll >> 1) & 3)) << 4) + jj * 2;
                *reinterpret_cast<uint32_t*>(Bs + off) = pk;
            }
        }
        if (tid < 32) {
            int ci = tid;
            int off = ((ci >> 3) << 4) + (ci & 7) * 2;        // ll=0, swz term 0
            *reinterpret_cast<unsigned short*>(Bs + off) = (unsigned short)f2bf(hReg);
        } else if (tid < 64) {
            int ci = tid - 32;  int ll = 129;
            int off = ll * 64 + (((ci >> 3) ^ ((ll >> 1) & 3)) << 4) + (ci & 7) * 2;
            *reinterpret_cast<unsigned short*>(Bs + off) = (unsigned short)f2bf(hReg);
        }
    };

    f32x4 acc[4][4];
#pragma unroll
    for (int i = 0; i < 4; ++i)
#pragma unroll
        for (int j = 0; j < 4; ++j) acc[i][j] = (f32x4){0.f, 0.f, 0.f, 0.f};

    // prologue
    LOADA(0); LOADB(0);
    WRITE();                       // compiler waits vmcnt on reg use

    for (int c = 0; c < 16; ++c) {
        if (c < 15) { LOADA(c + 1); LOADB(c + 1); }   // issue early, in flight across barrier
        asm volatile("s_waitcnt lgkmcnt(0)" ::: "memory");  // my ds_writes committed
        __builtin_amdgcn_s_barrier();
        __builtin_amdgcn_sched_barrier(0);

        // ---- compute chunk c: 3 taps x 4x4 MFMA ----
#pragma unroll
        for (int t = 0; t < KW; ++t) {
            bf16x8 afr[4], bfr[4];
#pragma unroll
            for (int ms = 0; ms < 4; ++ms)
                afr[ms] = *reinterpret_cast<const bf16x8*>(
                    As + ((t * 4 + ks) * 128 + wco + ms * 16 + m) * 16);
#pragma unroll
            for (int ns = 0; ns < 4; ++ns) {
                int ll = wl + ns * 16 + m + t;
                bfr[ns] = *reinterpret_cast<const bf16x8*>(
                    Bs + ll * 64 + ((ks ^ ((ll >> 1) & 3)) << 4));
            }
#pragma unroll
            for (int ms = 0; ms < 4; ++ms)
#pragma unroll
                for (int ns = 0; ns < 4; ++ns)
                    acc[ms][ns] = __builtin_amdgcn_mfma_f32_16x16x32_bf16(
                        afr[ms], bfr[ns], acc[ms][ns], 0, 0, 0);
        }

        __builtin_amdgcn_sched_barrier(0);
        __builtin_amdgcn_s_barrier();        // all waves done reading this chunk
        __builtin_amdgcn_sched_barrier(0);
        if (c < 15) WRITE();                 // overwrite LDS with chunk c+1
    }

    // ---- epilogue: D lane map col=lane&15, row=(lane>>4)*4+r ----
    float fscale = fac[0];
    int r4 = (lane >> 4) * 4;
#pragma unroll
    for (int ms = 0; ms < 4; ++ms) {
#pragma unroll
        for (int ns = 0; ns < 4; ++ns) {
            int col  = l0 + wl + ns * 16 + m;
            int row0 = co0 + wco + ms * 16 + r4;
            float* o = out + ((size_t)(n * 512 + row0)) * LLEN + col;
#pragma unroll
            for (int r = 0; r < 4; ++r)
                o[(size_t)r * LLEN] = acc[ms][ns][r] * fscale;
        }
    }
}

extern "C" void kernel_launch(void* const* d_in, const int* in_sizes, int n_in,
                              void* d_out, int out_size, void* d_ws, size_t ws_size,
                              hipStream_t stream) {
    const float* x     = (const float*)d_in[0];
    const float* w     = (const float*)d_in[1];
    const float* scale = (const float*)d_in[2];
    float* out = (float*)d_out;

    float* partials = (float*)d_ws;                               // 1024 floats
    float* fac      = (float*)((char*)d_ws + 4096);               // 1 float
    unsigned short* wsw = (unsigned short*)((char*)d_ws + 8192);  // 786432 bf16

    pack_w<<<(COUT * CIN) / 256, 256, 0, stream>>>(w, wsw, partials);
    wscale_final<<<1, 256, 0, stream>>>(partials, scale, fac);
    conv_mfma<<<NBAT * 4 * 32, 256, 0, stream>>>(x, wsw, fac, out);
}

// Round 3
// 141.331 us; speedup vs baseline: 2.6345x; 2.6345x over previous
//
#include <hip/hip_runtime.h>
#include <stdint.h>

// BitConv1d: out = conv1d(x, sign(w), pad=1) * mean|w| * scale
// (x_scale cancels exactly: conv(x/s,w)*s == conv(x,w))
//
// Workspace: float[1024] @0 partial |w| sums; float @4096 final factor;
//            ushort[786432] @8192 sign(w) bf16, layout [t][ci>>3][co][ci&7]

#define CIN   512
#define COUT  512
#define LLEN  4096
#define NBAT  16
#define KW    3
#define WELEMS (COUT*CIN*KW)

typedef __bf16 bf16x8 __attribute__((ext_vector_type(8)));
typedef float  f32x4  __attribute__((ext_vector_type(4)));

__device__ __forceinline__ uint32_t f2bf(float f) {
    union { float f; uint32_t u; } v; v.f = f;
    return (v.u + 0x7fffu + ((v.u >> 16) & 1u)) >> 16;   // RNE
}

// ---- pack sign(w) -> bf16 (MFMA layout) + per-block |w| partial sums ----
__global__ __launch_bounds__(256) void pack_w(const float* __restrict__ w,
                                              unsigned short* __restrict__ wsw,
                                              float* __restrict__ partial) {
    __shared__ float red[256];
    int tid = threadIdx.x;
    int idx = blockIdx.x * 256 + tid;          // co*512 + ci
    float s = 0.f;
    int co = idx >> 9, ci = idx & 511;
#pragma unroll
    for (int t = 0; t < KW; ++t) {
        float v = w[idx * 3 + t];
        s += fabsf(v);
        unsigned short b = (v > 0.f) ? 0x3F80 : ((v < 0.f) ? 0xBF80 : 0);
        wsw[((t * 64 + (ci >> 3)) * 512 + co) * 8 + (ci & 7)] = b;
    }
    red[tid] = s;
    __syncthreads();
    for (int off = 128; off > 0; off >>= 1) {
        if (tid < off) red[tid] += red[tid + off];
        __syncthreads();
    }
    if (tid == 0) partial[blockIdx.x] = red[0];
}

__global__ __launch_bounds__(256) void wscale_final(const float* __restrict__ partial,
                                                    const float* __restrict__ scale,
                                                    float* __restrict__ fac) {
    __shared__ float red[256];
    int tid = threadIdx.x;
    red[tid] = partial[tid] + partial[tid + 256] + partial[tid + 512] + partial[tid + 768];
    __syncthreads();
    for (int off = 128; off > 0; off >>= 1) {
        if (tid < off) red[tid] += red[tid + off];
        __syncthreads();
    }
    if (tid == 0) fac[0] = red[0] * (1.0f / (float)WELEMS) * scale[0];
}

// ---------------- conv as MFMA GEMM ----------------
// 128(co) x 128(l) block tile, 4 waves 2x2, acc 4x4.
// A (sign weights, 1.5MB total): NOT staged -- read per-tap from global (L2-hot).
// B (x tile): double-buffered LDS (2 x 8320B), reg-staged with issue-early /
// write-late split. Per iter, A loads are issued BEFORE B prefetch loads so
// counted vmcnt waits on A never drain the younger B loads (vmcnt is FIFO).
__global__ __launch_bounds__(256, 2) void conv_mfma(const float* __restrict__ x,
                                                    const unsigned short* __restrict__ wsw,
                                                    const float* __restrict__ fac,
                                                    float* __restrict__ out) {
    // XCD-aware bijective swizzle (2048 blocks % 8 == 0): the 4 cob-blocks
    // sharing an x tile run adjacent on one XCD -> x fetched ~once from HBM.
    int swz = (blockIdx.x & 7) * 256 + (blockIdx.x >> 3);
    int cob = swz & 3;
    int lb  = (swz >> 2) & 31;
    int n   = swz >> 7;
    int co0 = cob * 128;
    int l0  = lb * 128;

    __shared__ char Bs[2][8320];    // [ll 0..129][32 ci] bf16, 64B rows, XOR swizzle

    int tid  = threadIdx.x;
    int wave = tid >> 6;
    int lane = tid & 63;
    int wco  = (wave >> 1) * 64;
    int wl   = (wave & 1) * 64;
    int m    = lane & 15;
    int ks   = lane >> 4;
    const int p  = tid & 15;      // ci pair (2p, 2p+1)
    const int fb = tid >> 4;      // float4 column

    const float* xbase = x + (size_t)(n * 512) * LLEN;
    const char*  wb    = (const char*)wsw;

    // A per-lane byte offsets (invariant): elem ((t*64+c*4+ks)*512+co)*8, *2B
    int aoff[4];
#pragma unroll
    for (int ms = 0; ms < 4; ++ms)
        aoff[ms] = ks * 8192 + (co0 + wco + ms * 16 + m) * 16;

    // B prefetch registers (17 VGPRs live across compute -- no spill risk)
    float4 b0[2], b1[2];
    float  hReg = 0.f;

    auto LOADB = [&](int c) {
        const float* xrow0 = xbase + (size_t)(c * 32 + 2 * p) * LLEN + l0;
        const float* xrow1 = xrow0 + LLEN;
        b0[0] = reinterpret_cast<const float4*>(xrow0)[fb];
        b1[0] = reinterpret_cast<const float4*>(xrow1)[fb];
        b0[1] = reinterpret_cast<const float4*>(xrow0)[fb + 16];
        b1[1] = reinterpret_cast<const float4*>(xrow1)[fb + 16];
        if (tid < 32)
            hReg = (l0 > 0) ? xbase[(size_t)(c * 32 + tid) * LLEN + l0 - 1] : 0.f;
        else if (tid < 64)
            hReg = (l0 + 128 < LLEN) ? xbase[(size_t)(c * 32 + tid - 32) * LLEN + l0 + 128] : 0.f;
    };
    auto WRITEB = [&](char* BsD) {
        int kslot = p >> 2, jj = (2 * p) & 7;
#pragma unroll
        for (int half = 0; half < 2; ++half) {
#pragma unroll
            for (int e = 0; e < 4; ++e) {
                int ll = (fb + half * 16) * 4 + 1 + e;        // 1..128
                uint32_t pk = f2bf(((const float*)&b0[half])[e])
                            | (f2bf(((const float*)&b1[half])[e]) << 16);
                *reinterpret_cast<uint32_t*>(
                    BsD + ll * 64 + ((kslot ^ ((ll >> 1) & 3)) << 4) + jj * 2) = pk;
            }
        }
        if (tid < 32) {
            *reinterpret_cast<unsigned short*>(
                BsD + ((tid >> 3) << 4) + (tid & 7) * 2) = (unsigned short)f2bf(hReg);
        } else if (tid < 64) {
            int ci = tid - 32, ll = 129;
            *reinterpret_cast<unsigned short*>(
                BsD + ll * 64 + (((ci >> 3) ^ ((ll >> 1) & 3)) << 4) + (ci & 7) * 2)
                = (unsigned short)f2bf(hReg);
        }
    };

    f32x4 acc[4][4];
#pragma unroll
    for (int i = 0; i < 4; ++i)
#pragma unroll
        for (int j = 0; j < 4; ++j) acc[i][j] = (f32x4){0.f, 0.f, 0.f, 0.f};

    // prologue: stage chunk 0 of B
    LOADB(0);
    WRITEB(Bs[0]);
    __syncthreads();

    int cur = 0;
    for (int c = 0; c < 16; ++c) {
        // --- A loads for THIS chunk: oldest in the vmem queue ---
        bf16x8 afr[KW][4];
        {
            const char* ab = wb + c * 32768;
#pragma unroll
            for (int t = 0; t < KW; ++t)
#pragma unroll
                for (int ms = 0; ms < 4; ++ms)
                    afr[t][ms] = *reinterpret_cast<const bf16x8*>(
                        ab + t * 524288 + aoff[ms]);
        }
        __builtin_amdgcn_sched_barrier(0);   // keep B prefetch YOUNGER than A loads
        if (c < 15) LOADB(c + 1);            // in flight across the whole compute

        const char* Bc = Bs[cur];
#pragma unroll
        for (int t = 0; t < KW; ++t) {
            bf16x8 bfr[4];
#pragma unroll
            for (int ns = 0; ns < 4; ++ns) {
                int ll = wl + ns * 16 + m + t;
                bfr[ns] = *reinterpret_cast<const bf16x8*>(
                    Bc + ll * 64 + ((ks ^ ((ll >> 1) & 3)) << 4));
            }
#pragma unroll
            for (int ms = 0; ms < 4; ++ms)
#pragma unroll
                for (int ns = 0; ns < 4; ++ns)
                    acc[ms][ns] = __builtin_amdgcn_mfma_f32_16x16x32_bf16(
                        afr[t][ms], bfr[ns], acc[ms][ns], 0, 0, 0);
        }

        if (c < 15) {
            asm volatile("s_waitcnt vmcnt(0)" ::: "memory");   // B regs arrived
            WRITEB(Bs[cur ^ 1]);
            asm volatile("s_waitcnt lgkmcnt(0)" ::: "memory"); // my writes committed
            __builtin_amdgcn_s_barrier();                      // publish, no vm drain
        }
        cur ^= 1;
    }

    // ---- epilogue: D lane map col=lane&15, row=(lane>>4)*4+r ----
    float fscale = fac[0];
    int r4 = (lane >> 4) * 4;
#pragma unroll
    for (int ms = 0; ms < 4; ++ms) {
#pragma unroll
        for (int ns = 0; ns < 4; ++ns) {
            int col  = l0 + wl + ns * 16 + m;
            int row0 = co0 + wco + ms * 16 + r4;
            float* o = out + ((size_t)(n * 512 + row0)) * LLEN + col;
#pragma unroll
            for (int r = 0; r < 4; ++r)
                o[(size_t)r * LLEN] = acc[ms][ns][r] * fscale;
        }
    }
}

extern "C" void kernel_launch(void* const* d_in, const int* in_sizes, int n_in,
                              void* d_out, int out_size, void* d_ws, size_t ws_size,
                              hipStream_t stream) {
    const float* x     = (const float*)d_in[0];
    const float* w     = (const float*)d_in[1];
    const float* scale = (const float*)d_in[2];
    float* out = (float*)d_out;

    float* partials = (float*)d_ws;                               // 1024 floats
    float* fac      = (float*)((char*)d_ws + 4096);               // 1 float
    unsigned short* wsw = (unsigned short*)((char*)d_ws + 8192);  // 786432 bf16

    pack_w<<<(COUT * CIN) / 256, 256, 0, stream>>>(w, wsw, partials);
    wscale_final<<<1, 256, 0, stream>>>(partials, scale, fac);
    conv_mfma<<<NBAT * 4 * 32, 256, 0, stream>>>(x, wsw, fac, out);
}